// Round 4
// baseline (218.049 us; speedup 1.0000x reference)
//
#include <hip/hip_runtime.h>
#include <hip/hip_bf16.h>

typedef __attribute__((ext_vector_type(4))) float floatx4;
typedef __attribute__((ext_vector_type(8))) short short8;

#define HIDDEN 256
#define NOUT 16384   // GDIM*GDIM*GROUPS = 64*64*4

static __device__ __forceinline__ short bf16bits(float x) {
    __hip_bfloat16 h = __float2bfloat16(x);
    return __builtin_bit_cast(short, h);
}

// channel permutation: original channel c -> permuted position p (kB's fragment read order).
// k-within-group order chosen so kB's x loads are 64 B-contiguous per row:
//   d = ks*32 + half*16 + quad*4 + jj,  j = half*4 + jj  (lane slot j, lane quad)
static __device__ __forceinline__ int permc(int c) {
    const int g = c >> 12, e = (c >> 6) & 63, d = c & 63;
    const int nt = e >> 4, lq = e & 15;
    const int ks = d >> 5, half = (d >> 4) & 1, quad = (d >> 2) & 3, jj = d & 3;
    const int j = half * 4 + jj;
    return ((((g << 2) | nt) << 1 | ks) << 9) | (((quad << 4) | lq) << 3) | j;
}
// inverse: permuted position p -> original channel c
static __device__ __forceinline__ int invperm(int p) {
    const int blk = p >> 9, g = blk >> 3, nt = (blk >> 1) & 3, ks = blk & 1;
    const int r = (p >> 3) & 63, quad = r >> 4, lq = r & 15;
    const int j = p & 7, half = j >> 2, jj = j & 3;
    return g * 4096 + (nt * 16 + lq) * 64 + ks * 32 + half * 16 + quad * 4 + jj;
}

// ---------------- kPrep ----------------
// Wg fp32 -> WgF: bf16, transposed, channel-permuted AND fragment-tiled:
//   WgF[nT][q][lq][j]  (nT = prow>>4, lq = prow&15, k = q*8+j)
// so a wave's b-fragment load in kA is lane-contiguous 1 KB.
// qc fp32 -> qcF: bf16, same fragment tiling over rows.
__global__ __launch_bounds__(256) void kPrep(
    const float* __restrict__ Wg, short* __restrict__ WgF,
    const float* __restrict__ qc, short* __restrict__ qcF, int n4)
{
    __shared__ short t[64 * 68];
    const int tid = threadIdx.x;

    if (blockIdx.x < 1024) {
        const int n0 = (blockIdx.x & 255) * 64, k0 = (blockIdx.x >> 8) * 64;
        // phase 1: coalesced read along n, write t[kl][nl] (bf16)
        const int r  = tid >> 4;
        const int c4 = tid & 15;
        #pragma unroll
        for (int i = 0; i < 4; ++i) {
            const int kl = r + i * 16;
            float4 f = *reinterpret_cast<const float4*>(Wg + (size_t)(k0 + kl) * NOUT + n0 + c4 * 4);
            short4 v;
            v.x = bf16bits(f.x); v.y = bf16bits(f.y); v.z = bf16bits(f.z); v.w = bf16bits(f.w);
            *reinterpret_cast<short4*>(&t[kl * 68 + c4 * 4]) = v;
        }
        __syncthreads();
        // phase 2: gather k-contiguous, b128 store to fragment-tiled position
        #pragma unroll
        for (int h = 0; h < 2; ++h) {
            const int id = tid + h * 256;
            const int nl = id >> 3, kc = id & 7;
            short8 v;
            #pragma unroll
            for (int j = 0; j < 8; ++j) v[j] = t[(kc * 8 + j) * 68 + nl];
            const int prow = permc(n0 + nl);
            const int q = (k0 >> 3) + kc;            // k-chunk index 0..31
            *reinterpret_cast<short8*>(WgF + (size_t)(prow >> 4) * 4096 + q * 128 + (prow & 15) * 8) = v;
        }
    } else {
        const int i = (blockIdx.x - 1024) * 256 + tid;
        if (i < n4) {
            float4 f = reinterpret_cast<const float4*>(qc)[i];
            short4 v;
            v.x = bf16bits(f.x); v.y = bf16bits(f.y); v.z = bf16bits(f.z); v.w = bf16bits(f.w);
            const int m = i >> 6, k4 = i & 63;       // row, float4-index within row
            const int off = (m >> 4) * 4096 + (k4 >> 1) * 128 + (m & 15) * 8 + (k4 & 1) * 4;
            *reinterpret_cast<short4*>(qcF + off) = v;
        }
    }
}

// ---------------- kA6: wdyn_perm[M,16384] = bf16(qcF @ WgF^T + bg∘inv) ----------------
// Zero-LDS-staging GEMM: both operands fragment-tiled -> every A/B fragment load is a
// contiguous per-wave 1 KB dwordx4 straight to registers. No barriers / vmcnt(0) drains
// in the K-loop; 2-deep ping-pong prefetch. XCD-aware remap: 8 XCDs x 16 B-panels x
// nMB m-blocks so each XCD's 1 MB B-slice stays L2-resident across the m-sweep.
__global__ __launch_bounds__(256) void kA6(
    const short* __restrict__ qcF, const short* __restrict__ WgF,
    const float* __restrict__ bg, short* __restrict__ wdyn, int M)
{
    __shared__ short Cs[64 * 128];   // 16 KB, epilogue restage only

    const int tid  = threadIdx.x;
    const int wave = tid >> 6, lane = tid & 63;
    const int lq   = lane & 15, quad = lane >> 4;
    const int wm   = wave >> 1, wn = wave & 1;

    const int wgid = blockIdx.x;
    const int xcd  = wgid & 7;
    const int c    = wgid >> 3;
    const int nMB  = gridDim.x >> 7;          // number of m-blocks (19)
    const int pl   = c / nMB;                 // panel-local index 0..15
    const int mi   = c - pl * nMB;            // m-block 0..nMB-1
    const int m0   = mi * 128;
    const int n0   = (xcd * 16 + pl) * 128;

    const int mtMax = M >> 4;                 // valid 16-row tiles (M % 16 == 0)
    const int mT0 = (m0 >> 4) + wm * 4;
    const int nT0 = (n0 >> 4) + wn * 4;

    const short* aB[4]; const short* bB[4];
    #pragma unroll
    for (int i = 0; i < 4; ++i) {
        int mT = mT0 + i; if (mT >= mtMax) mT = 0;   // clamp: garbage rows masked at store
        aB[i] = qcF + (size_t)mT * 4096 + lane * 8;
        bB[i] = WgF + (size_t)(nT0 + i) * 4096 + lane * 8;
    }

    floatx4 acc[4][4];
    #pragma unroll
    for (int i = 0; i < 4; ++i)
        #pragma unroll
        for (int j = 0; j < 4; ++j) acc[i][j] = (floatx4){0.f, 0.f, 0.f, 0.f};

    // K = 256 = 8 steps of 32; fragment for step: base + step*512 shorts (1 KB), lane*16B.
    short8 A[2][4], B[2][4];
    #pragma unroll
    for (int i = 0; i < 4; ++i) {
        A[0][i] = *reinterpret_cast<const short8*>(aB[i]);
        B[0][i] = *reinterpret_cast<const short8*>(bB[i]);
    }
    #pragma unroll
    for (int step = 0; step < 8; ++step) {
        const int cur = step & 1, nxt = cur ^ 1;
        if (step < 7) {
            #pragma unroll
            for (int i = 0; i < 4; ++i) {
                A[nxt][i] = *reinterpret_cast<const short8*>(aB[i] + (step + 1) * 512);
                B[nxt][i] = *reinterpret_cast<const short8*>(bB[i] + (step + 1) * 512);
            }
        }
        #pragma unroll
        for (int i = 0; i < 4; ++i)
            #pragma unroll
            for (int j = 0; j < 4; ++j)
                acc[i][j] = __builtin_amdgcn_mfma_f32_16x16x32_bf16(A[cur][i], B[cur][j], acc[i][j], 0, 0, 0);
    }

    // bias via inverse channel permutation (bg is 64 KB, cache-resident)
    float bv[4];
    #pragma unroll
    for (int j = 0; j < 4; ++j) bv[j] = bg[invperm(n0 + wn * 64 + j * 16 + lq)];

    // epilogue: restage through LDS (64x128 bf16), coalesced stores
    #pragma unroll
    for (int half = 0; half < 2; ++half) {
        if (half) __syncthreads();
        if (wm == half) {
            #pragma unroll
            for (int j = 0; j < 4; ++j)
                #pragma unroll
                for (int i = 0; i < 4; ++i)
                    #pragma unroll
                    for (int r = 0; r < 4; ++r)
                        Cs[(i * 16 + quad * 4 + r) * 128 + wn * 64 + j * 16 + lq] =
                            bf16bits(acc[i][j][r] + bv[j]);
        }
        __syncthreads();
        #pragma unroll
        for (int t = 0; t < 4; ++t) {
            const int id = t * 256 + tid;
            const int mr = id >> 4, ch = id & 15;
            const int grow = m0 + half * 64 + mr;
            if (grow < M)
                *reinterpret_cast<short8*>(&wdyn[(size_t)grow * NOUT + n0 + ch * 8]) =
                    *reinterpret_cast<const short8*>(&Cs[mr * 128 + ch * 8]);
        }
    }
}

// ---------------- kB7: per (b,n): grouped mix + in-register LayerNorm + ReLU ----------------
// Swapped-operand MFMA (D[c][p]) for the cheap 2-shfl LN. NEW k-order within group
// (d = ks*32 + half*16 + quad*4 + jj) so each x-load instruction reads 64 B-contiguous
// segments per row (4 lanes x 16 B merge) instead of 64 isolated 16 B chunks — 4x fewer
// x-path transactions (x was 1024 of 1280 txns/block; kernel sat at 3.5 TB/s request-bound).
// Output restaged through a 16 KB XOR-swizzled LDS buffer: contiguous 1 KB/wave NT stores.
__global__ __launch_bounds__(256) void kB7(
    const float* __restrict__ x, const short* __restrict__ wdyn,
    const float* __restrict__ gamma, const float* __restrict__ beta,
    float* __restrict__ out)
{
    __shared__ float ots[16 * 256];      // 16 KB epilogue restage (2 passes of 16 rows)
    __shared__ float red[2][2][16][2];   // [mtile][gp][lq][s/ss] = 512 B

    const int tid  = threadIdx.x;
    const int bnq  = blockIdx.x;
    const int wave = tid >> 6, lane = tid & 63;
    const int lq   = lane & 15, quad = lane >> 4;
    const int mtile = wave & 1, gp = wave >> 1;

    const float* xr = x + (size_t)bnq * (32 * HIDDEN) + (mtile * 16 + lq) * HIDDEN;
    const short* wr = wdyn + (size_t)bnq * NOUT + lane * 8;

    // x loads: per (gi,ks), lane (lq,quad) reads float4 at quad*4 and quad*4+16:
    // instruction-level addresses are 4-lane 64 B-contiguous runs per row.
    floatx4 xf[2][2][2];
    #pragma unroll
    for (int gi = 0; gi < 2; ++gi) {
        const int g = gp * 2 + gi;
        #pragma unroll
        for (int ks = 0; ks < 2; ++ks) {
            const float* s = xr + g * 64 + ks * 32 + quad * 4;
            xf[gi][ks][0] = __builtin_nontemporal_load(reinterpret_cast<const floatx4*>(s));
            xf[gi][ks][1] = __builtin_nontemporal_load(reinterpret_cast<const floatx4*>(s + 16));
        }
    }
    short8 afr[2][2];
    #pragma unroll
    for (int gi = 0; gi < 2; ++gi)
        #pragma unroll
        for (int ks = 0; ks < 2; ++ks) {
            const floatx4 f0 = xf[gi][ks][0];   // j = 0..3  (d = ks*32 + quad*4 + jj)
            const floatx4 f1 = xf[gi][ks][1];   // j = 4..7  (d = ks*32 + 16 + quad*4 + jj)
            short8 v;
            v[0]=bf16bits(f0[0]); v[1]=bf16bits(f0[1]); v[2]=bf16bits(f0[2]); v[3]=bf16bits(f0[3]);
            v[4]=bf16bits(f1[0]); v[5]=bf16bits(f1[1]); v[6]=bf16bits(f1[2]); v[7]=bf16bits(f1[3]);
            afr[gi][ks] = v;
        }

    floatx4 acc[2][4];
    #pragma unroll
    for (int gi = 0; gi < 2; ++gi)
        #pragma unroll
        for (int nt = 0; nt < 4; ++nt) acc[gi][nt] = (floatx4){0.f, 0.f, 0.f, 0.f};

    // SWAPPED operands: D[c][p] — lane&15 = p, (lane>>4)*4+r = channel offset.
    #pragma unroll
    for (int gi = 0; gi < 2; ++gi) {
        const int g = gp * 2 + gi;
        #pragma unroll
        for (int ks = 0; ks < 2; ++ks) {
            short8 b[4];
            #pragma unroll
            for (int nt = 0; nt < 4; ++nt)
                b[nt] = *reinterpret_cast<const short8*>(
                    wr + (((((g << 2) | nt) << 1) | ks) << 9));
            #pragma unroll
            for (int nt = 0; nt < 4; ++nt)
                acc[gi][nt] = __builtin_amdgcn_mfma_f32_16x16x32_bf16(
                    b[nt], afr[gi][ks], acc[gi][nt], 0, 0, 0);
        }
    }

    // LN reduction: each lane's 32 values all belong to row p = mtile*16+lq.
    float s = 0.f, ss = 0.f;
    #pragma unroll
    for (int gi = 0; gi < 2; ++gi)
        #pragma unroll
        for (int nt = 0; nt < 4; ++nt)
            #pragma unroll
            for (int r = 0; r < 4; ++r) {
                const float v = acc[gi][nt][r];
                s += v; ss += v * v;
            }
    s  += __shfl_xor(s, 16);  ss += __shfl_xor(ss, 16);
    s  += __shfl_xor(s, 32);  ss += __shfl_xor(ss, 32);

    if (quad == 0) { red[mtile][gp][lq][0] = s; red[mtile][gp][lq][1] = ss; }
    __syncthreads();

    const float S  = s  + red[mtile][gp ^ 1][lq][0];
    const float SS = ss + red[mtile][gp ^ 1][lq][1];
    const float mu = S * (1.f / 256.f);
    float var = SS * (1.f / 256.f) - mu * mu;
    var = fmaxf(var, 0.f);
    const float rs = rsqrtf(var + 1e-5f);

    // normalize + affine + relu in place
    #pragma unroll
    for (int gi = 0; gi < 2; ++gi) {
        const int g = gp * 2 + gi;
        #pragma unroll
        for (int nt = 0; nt < 4; ++nt) {
            const int c0 = g * 64 + nt * 16 + quad * 4;
            const floatx4 gm = *reinterpret_cast<const floatx4*>(gamma + c0);
            const floatx4 bt = *reinterpret_cast<const floatx4*>(beta + c0);
            #pragma unroll
            for (int r = 0; r < 4; ++r)
                acc[gi][nt][r] = fmaxf((acc[gi][nt][r] - mu) * rs * gm[r] + bt[r], 0.f);
        }
    }

    // epilogue: two 16-row passes through swizzled LDS; fully coalesced global stores.
    floatx4* ots4 = reinterpret_cast<floatx4*>(ots);
    floatx4* obase = reinterpret_cast<floatx4*>(out + (size_t)bnq * (32 * HIDDEN));
    #pragma unroll
    for (int h = 0; h < 2; ++h) {
        if (h) __syncthreads();
        if (mtile == h) {
            #pragma unroll
            for (int gi = 0; gi < 2; ++gi) {
                const int g = gp * 2 + gi;
                #pragma unroll
                for (int nt = 0; nt < 4; ++nt) {
                    const int c4 = g * 16 + nt * 4 + quad;
                    ots4[(lq * 64 + c4) ^ (lq & 7)] = acc[gi][nt];
                }
            }
        }
        __syncthreads();
        #pragma unroll
        for (int t = 0; t < 4; ++t) {
            const int sl = t * 256 + tid;
            const int pl = sl >> 6;                    // constant per wave
            const floatx4 v = ots4[sl ^ (pl & 7)];
            __builtin_nontemporal_store(v, obase + h * 1024 + sl);
        }
    }
}

extern "C" void kernel_launch(void* const* d_in, const int* in_sizes, int n_in,
                              void* d_out, int out_size, void* d_ws, size_t ws_size,
                              hipStream_t stream)
{
    const float* x     = (const float*)d_in[0];
    const float* qc    = (const float*)d_in[1];
    const float* Wg    = (const float*)d_in[2];
    const float* bg    = (const float*)d_in[3];
    const float* gamma = (const float*)d_in[4];
    const float* beta  = (const float*)d_in[5];
    float* out = (float*)d_out;

    const int M = in_sizes[1] / HIDDEN;   // B*N = 2400

    // workspace layout (bytes)
    char* ws = (char*)d_ws;
    short* wdyn = (short*)ws;                                    // M*16384*2
    short* WgF  = (short*)(ws + (size_t)M * NOUT * 2);           // 16384*256*2
    short* qcF  = (short*)(ws + (size_t)M * NOUT * 2 + (size_t)NOUT * HIDDEN * 2);

    const int n4 = (M * HIDDEN) / 4;
    const int prepBlocks = 1024 + (n4 + 255) / 256;
    kPrep<<<prepBlocks, 256, 0, stream>>>(Wg, WgF, qc, qcF, n4);

    const int nMB = (M + 127) / 128;      // 19
    kA6<<<nMB * 128, 256, 0, stream>>>(qcF, WgF, bg, wdyn, M);

    kB7<<<M, 256, 0, stream>>>(x, wdyn, gamma, beta, out);
}

// Round 5
// 216.903 us; speedup vs baseline: 1.0053x; 1.0053x over previous
//
#include <hip/hip_runtime.h>
#include <hip/hip_bf16.h>

typedef __attribute__((ext_vector_type(4))) float floatx4;
typedef __attribute__((ext_vector_type(8))) short short8;

#define HIDDEN 256
#define NOUT 16384   // GDIM*GDIM*GROUPS = 64*64*4

static __device__ __forceinline__ short bf16bits(float x) {
    __hip_bfloat16 h = __float2bfloat16(x);
    return __builtin_bit_cast(short, h);
}

// channel permutation: original channel c -> permuted position p (kB's fragment read order).
// k-within-group order chosen so kB's x loads are 64 B-contiguous per row:
//   d = ks*32 + half*16 + quad*4 + jj,  j = half*4 + jj  (lane slot j, lane quad)
static __device__ __forceinline__ int permc(int c) {
    const int g = c >> 12, e = (c >> 6) & 63, d = c & 63;
    const int nt = e >> 4, lq = e & 15;
    const int ks = d >> 5, half = (d >> 4) & 1, quad = (d >> 2) & 3, jj = d & 3;
    const int j = half * 4 + jj;
    return ((((g << 2) | nt) << 1 | ks) << 9) | (((quad << 4) | lq) << 3) | j;
}
// inverse: permuted position p -> original channel c
static __device__ __forceinline__ int invperm(int p) {
    const int blk = p >> 9, g = blk >> 3, nt = (blk >> 1) & 3, ks = blk & 1;
    const int r = (p >> 3) & 63, quad = r >> 4, lq = r & 15;
    const int j = p & 7, half = j >> 2, jj = j & 3;
    return g * 4096 + (nt * 16 + lq) * 64 + ks * 32 + half * 16 + quad * 4 + jj;
}

// ---------------- kPrep ----------------
// Wg fp32 -> WgF: bf16, transposed, channel-permuted AND fragment-tiled:
//   WgF[nT][q][lq][j]  (nT = prow>>4, lq = prow&15, k = q*8+j)
// so a wave's b-fragment load in kA is lane-contiguous 1 KB.
// qc fp32 -> qcF: bf16, same fragment tiling over rows.
__global__ __launch_bounds__(256) void kPrep(
    const float* __restrict__ Wg, short* __restrict__ WgF,
    const float* __restrict__ qc, short* __restrict__ qcF, int n4)
{
    __shared__ short t[64 * 68];
    const int tid = threadIdx.x;

    if (blockIdx.x < 1024) {
        const int n0 = (blockIdx.x & 255) * 64, k0 = (blockIdx.x >> 8) * 64;
        // phase 1: coalesced read along n, write t[kl][nl] (bf16)
        const int r  = tid >> 4;
        const int c4 = tid & 15;
        #pragma unroll
        for (int i = 0; i < 4; ++i) {
            const int kl = r + i * 16;
            float4 f = *reinterpret_cast<const float4*>(Wg + (size_t)(k0 + kl) * NOUT + n0 + c4 * 4);
            short4 v;
            v.x = bf16bits(f.x); v.y = bf16bits(f.y); v.z = bf16bits(f.z); v.w = bf16bits(f.w);
            *reinterpret_cast<short4*>(&t[kl * 68 + c4 * 4]) = v;
        }
        __syncthreads();
        // phase 2: gather k-contiguous, b128 store to fragment-tiled position
        #pragma unroll
        for (int h = 0; h < 2; ++h) {
            const int id = tid + h * 256;
            const int nl = id >> 3, kc = id & 7;
            short8 v;
            #pragma unroll
            for (int j = 0; j < 8; ++j) v[j] = t[(kc * 8 + j) * 68 + nl];
            const int prow = permc(n0 + nl);
            const int q = (k0 >> 3) + kc;            // k-chunk index 0..31
            *reinterpret_cast<short8*>(WgF + (size_t)(prow >> 4) * 4096 + q * 128 + (prow & 15) * 8) = v;
        }
    } else {
        const int i = (blockIdx.x - 1024) * 256 + tid;
        if (i < n4) {
            float4 f = reinterpret_cast<const float4*>(qc)[i];
            short4 v;
            v.x = bf16bits(f.x); v.y = bf16bits(f.y); v.z = bf16bits(f.z); v.w = bf16bits(f.w);
            const int m = i >> 6, k4 = i & 63;       // row, float4-index within row
            const int off = (m >> 4) * 4096 + (k4 >> 1) * 128 + (m & 15) * 8 + (k4 & 1) * 4;
            *reinterpret_cast<short4*>(qcF + off) = v;
        }
    }
}

// ---------------- kA6: wdyn_perm[M,16384] = bf16(qcF @ WgF^T + bg∘inv) ----------------
// Zero-LDS-staging GEMM: both operands fragment-tiled -> every A/B fragment load is a
// contiguous per-wave 1 KB dwordx4 straight to registers. No barriers / vmcnt(0) drains
// in the K-loop; 2-deep ping-pong prefetch. XCD-aware remap: 8 XCDs x 16 B-panels x
// nMB m-blocks so each XCD's 1 MB B-slice stays L2-resident across the m-sweep.
__global__ __launch_bounds__(256) void kA6(
    const short* __restrict__ qcF, const short* __restrict__ WgF,
    const float* __restrict__ bg, short* __restrict__ wdyn, int M)
{
    __shared__ short Cs[64 * 128];   // 16 KB, epilogue restage only

    const int tid  = threadIdx.x;
    const int wave = tid >> 6, lane = tid & 63;
    const int lq   = lane & 15, quad = lane >> 4;
    const int wm   = wave >> 1, wn = wave & 1;

    const int wgid = blockIdx.x;
    const int xcd  = wgid & 7;
    const int c    = wgid >> 3;
    const int nMB  = gridDim.x >> 7;          // number of m-blocks (19)
    const int pl   = c / nMB;                 // panel-local index 0..15
    const int mi   = c - pl * nMB;            // m-block 0..nMB-1
    const int m0   = mi * 128;
    const int n0   = (xcd * 16 + pl) * 128;

    const int mtMax = M >> 4;                 // valid 16-row tiles (M % 16 == 0)
    const int mT0 = (m0 >> 4) + wm * 4;
    const int nT0 = (n0 >> 4) + wn * 4;

    const short* aB[4]; const short* bB[4];
    #pragma unroll
    for (int i = 0; i < 4; ++i) {
        int mT = mT0 + i; if (mT >= mtMax) mT = 0;   // clamp: garbage rows masked at store
        aB[i] = qcF + (size_t)mT * 4096 + lane * 8;
        bB[i] = WgF + (size_t)(nT0 + i) * 4096 + lane * 8;
    }

    floatx4 acc[4][4];
    #pragma unroll
    for (int i = 0; i < 4; ++i)
        #pragma unroll
        for (int j = 0; j < 4; ++j) acc[i][j] = (floatx4){0.f, 0.f, 0.f, 0.f};

    // K = 256 = 8 steps of 32; fragment for step: base + step*512 shorts (1 KB), lane*16B.
    short8 A[2][4], B[2][4];
    #pragma unroll
    for (int i = 0; i < 4; ++i) {
        A[0][i] = *reinterpret_cast<const short8*>(aB[i]);
        B[0][i] = *reinterpret_cast<const short8*>(bB[i]);
    }
    #pragma unroll
    for (int step = 0; step < 8; ++step) {
        const int cur = step & 1, nxt = cur ^ 1;
        if (step < 7) {
            #pragma unroll
            for (int i = 0; i < 4; ++i) {
                A[nxt][i] = *reinterpret_cast<const short8*>(aB[i] + (step + 1) * 512);
                B[nxt][i] = *reinterpret_cast<const short8*>(bB[i] + (step + 1) * 512);
            }
        }
        #pragma unroll
        for (int i = 0; i < 4; ++i)
            #pragma unroll
            for (int j = 0; j < 4; ++j)
                acc[i][j] = __builtin_amdgcn_mfma_f32_16x16x32_bf16(A[cur][i], B[cur][j], acc[i][j], 0, 0, 0);
    }

    // bias via inverse channel permutation (bg is 64 KB, cache-resident)
    float bv[4];
    #pragma unroll
    for (int j = 0; j < 4; ++j) bv[j] = bg[invperm(n0 + wn * 64 + j * 16 + lq)];

    // epilogue: restage through LDS (64x128 bf16), coalesced stores
    #pragma unroll
    for (int half = 0; half < 2; ++half) {
        if (half) __syncthreads();
        if (wm == half) {
            #pragma unroll
            for (int j = 0; j < 4; ++j)
                #pragma unroll
                for (int i = 0; i < 4; ++i)
                    #pragma unroll
                    for (int r = 0; r < 4; ++r)
                        Cs[(i * 16 + quad * 4 + r) * 128 + wn * 64 + j * 16 + lq] =
                            bf16bits(acc[i][j][r] + bv[j]);
        }
        __syncthreads();
        #pragma unroll
        for (int t = 0; t < 4; ++t) {
            const int id = t * 256 + tid;
            const int mr = id >> 4, ch = id & 15;
            const int grow = m0 + half * 64 + mr;
            if (grow < M)
                *reinterpret_cast<short8*>(&wdyn[(size_t)grow * NOUT + n0 + ch * 8]) =
                    *reinterpret_cast<const short8*>(&Cs[mr * 128 + ch * 8]);
        }
    }
}

// ---------------- kB8: 2-query pipelined: grouped mix + in-register LayerNorm + ReLU ----------------
// Each block processes bnq = 2*blockIdx.x and +1. Both queries' x loads (HBM, the long-
// latency path) are issued back-to-back up front, so q1's 16 loads ride in flight under
// q0's entire compute+LN+epilogue (~10 us of cover). Removes one exposed x-latency round
// per 2 queries and halves the per-work count of dead epilogue tails (kB7: 2.6 blocks/CU
// resident, 13 us lifetime for 96 KB -> head/tail stall was the 3.5 TB/s cap, not
// granularity). VGPR grows to ~110: intentionally inside the <=128 band (16-wave/CU cap;
// observed residency 10.5 waves, so no cap hit). LDS reused across queries; q1's LN
// barrier orders q0's final ots reads before q1's ots writes.
__global__ __launch_bounds__(256) void kB8(
    const float* __restrict__ x, const short* __restrict__ wdyn,
    const float* __restrict__ gamma, const float* __restrict__ beta,
    float* __restrict__ out, int M)
{
    __shared__ float ots[16 * 256];      // 16 KB epilogue restage (2 passes of 16 rows)
    __shared__ float red[2][2][16][2];   // [mtile][gp][lq][s/ss] = 512 B

    const int tid  = threadIdx.x;
    const int wave = tid >> 6, lane = tid & 63;
    const int lq   = lane & 15, quad = lane >> 4;
    const int mtile = wave & 1, gp = wave >> 1;

    const int q0 = blockIdx.x * 2, q1 = q0 + 1;
    const bool has1 = (q1 < M);

    // ---- issue x loads for a query (16 B/lane, 64 B-contiguous per row) ----
    auto issueX = [&](int bnq, floatx4 (&xf)[2][2][2]) {
        const float* xr = x + (size_t)bnq * (32 * HIDDEN) + (mtile * 16 + lq) * HIDDEN;
        #pragma unroll
        for (int gi = 0; gi < 2; ++gi) {
            const int g = gp * 2 + gi;
            #pragma unroll
            for (int ks = 0; ks < 2; ++ks) {
                const float* s = xr + g * 64 + ks * 32 + quad * 4;
                xf[gi][ks][0] = __builtin_nontemporal_load(reinterpret_cast<const floatx4*>(s));
                xf[gi][ks][1] = __builtin_nontemporal_load(reinterpret_cast<const floatx4*>(s + 16));
            }
        }
    };
    auto cvt = [&](const floatx4 (&xf)[2][2][2], short8 (&afr)[2][2]) {
        #pragma unroll
        for (int gi = 0; gi < 2; ++gi)
            #pragma unroll
            for (int ks = 0; ks < 2; ++ks) {
                const floatx4 f0 = xf[gi][ks][0];   // j = 0..3  (d = ks*32 + quad*4 + jj)
                const floatx4 f1 = xf[gi][ks][1];   // j = 4..7  (d = ks*32 + 16 + quad*4 + jj)
                short8 v;
                v[0]=bf16bits(f0[0]); v[1]=bf16bits(f0[1]); v[2]=bf16bits(f0[2]); v[3]=bf16bits(f0[3]);
                v[4]=bf16bits(f1[0]); v[5]=bf16bits(f1[1]); v[6]=bf16bits(f1[2]); v[7]=bf16bits(f1[3]);
                afr[gi][ks] = v;
            }
    };

    // ---- full per-query pipeline: wdyn MFMA + LN + epilogue ----
    auto runQuery = [&](int bnq, const short8 (&afr)[2][2]) {
        const short* wr = wdyn + (size_t)bnq * NOUT + lane * 8;

        floatx4 acc[2][4];
        #pragma unroll
        for (int gi = 0; gi < 2; ++gi)
            #pragma unroll
            for (int nt = 0; nt < 4; ++nt) acc[gi][nt] = (floatx4){0.f, 0.f, 0.f, 0.f};

        // SWAPPED operands: D[c][p] — lane&15 = p, (lane>>4)*4+r = channel offset.
        #pragma unroll
        for (int gi = 0; gi < 2; ++gi) {
            const int g = gp * 2 + gi;
            #pragma unroll
            for (int ks = 0; ks < 2; ++ks) {
                short8 b[4];
                #pragma unroll
                for (int nt = 0; nt < 4; ++nt)
                    b[nt] = *reinterpret_cast<const short8*>(
                        wr + (((((g << 2) | nt) << 1) | ks) << 9));
                #pragma unroll
                for (int nt = 0; nt < 4; ++nt)
                    acc[gi][nt] = __builtin_amdgcn_mfma_f32_16x16x32_bf16(
                        b[nt], afr[gi][ks], acc[gi][nt], 0, 0, 0);
            }
        }

        // LN reduction: each lane's 32 values all belong to row p = mtile*16+lq.
        float s = 0.f, ss = 0.f;
        #pragma unroll
        for (int gi = 0; gi < 2; ++gi)
            #pragma unroll
            for (int nt = 0; nt < 4; ++nt)
                #pragma unroll
                for (int r = 0; r < 4; ++r) {
                    const float v = acc[gi][nt][r];
                    s += v; ss += v * v;
                }
        s  += __shfl_xor(s, 16);  ss += __shfl_xor(ss, 16);
        s  += __shfl_xor(s, 32);  ss += __shfl_xor(ss, 32);

        if (quad == 0) { red[mtile][gp][lq][0] = s; red[mtile][gp][lq][1] = ss; }
        __syncthreads();

        const float S  = s  + red[mtile][gp ^ 1][lq][0];
        const float SS = ss + red[mtile][gp ^ 1][lq][1];
        const float mu = S * (1.f / 256.f);
        float var = SS * (1.f / 256.f) - mu * mu;
        var = fmaxf(var, 0.f);
        const float rs = rsqrtf(var + 1e-5f);

        // normalize + affine + relu in place
        #pragma unroll
        for (int gi = 0; gi < 2; ++gi) {
            const int g = gp * 2 + gi;
            #pragma unroll
            for (int nt = 0; nt < 4; ++nt) {
                const int c0 = g * 64 + nt * 16 + quad * 4;
                const floatx4 gm = *reinterpret_cast<const floatx4*>(gamma + c0);
                const floatx4 bt = *reinterpret_cast<const floatx4*>(beta + c0);
                #pragma unroll
                for (int r = 0; r < 4; ++r)
                    acc[gi][nt][r] = fmaxf((acc[gi][nt][r] - mu) * rs * gm[r] + bt[r], 0.f);
            }
        }

        // epilogue: two 16-row passes through swizzled LDS; fully coalesced global stores.
        floatx4* ots4 = reinterpret_cast<floatx4*>(ots);
        floatx4* obase = reinterpret_cast<floatx4*>(out + (size_t)bnq * (32 * HIDDEN));
        #pragma unroll
        for (int h = 0; h < 2; ++h) {
            if (h) __syncthreads();
            if (mtile == h) {
                #pragma unroll
                for (int gi = 0; gi < 2; ++gi) {
                    const int g = gp * 2 + gi;
                    #pragma unroll
                    for (int nt = 0; nt < 4; ++nt) {
                        const int c4 = g * 16 + nt * 4 + quad;
                        ots4[(lq * 64 + c4) ^ (lq & 7)] = acc[gi][nt];
                    }
                }
            }
            __syncthreads();
            #pragma unroll
            for (int t = 0; t < 4; ++t) {
                const int sl = t * 256 + tid;
                const int pl = sl >> 6;                    // constant per wave
                const floatx4 v = ots4[sl ^ (pl & 7)];
                __builtin_nontemporal_store(v, obase + h * 1024 + sl);
            }
        }
    };

    floatx4 xfA[2][2][2], xfB[2][2][2];
    short8 afrA[2][2], afrB[2][2];

    issueX(q0, xfA);
    if (has1) issueX(q1, xfB);    // q1's HBM loads in flight under all of q0's work
    cvt(xfA, afrA);               // waits only until xfA lands (vmcnt leaves xfB out)
    runQuery(q0, afrA);
    if (has1) {
        cvt(xfB, afrB);           // already landed — no exposed latency
        runQuery(q1, afrB);
    }
}

extern "C" void kernel_launch(void* const* d_in, const int* in_sizes, int n_in,
                              void* d_out, int out_size, void* d_ws, size_t ws_size,
                              hipStream_t stream)
{
    const float* x     = (const float*)d_in[0];
    const float* qc    = (const float*)d_in[1];
    const float* Wg    = (const float*)d_in[2];
    const float* bg    = (const float*)d_in[3];
    const float* gamma = (const float*)d_in[4];
    const float* beta  = (const float*)d_in[5];
    float* out = (float*)d_out;

    const int M = in_sizes[1] / HIDDEN;   // B*N = 2400

    // workspace layout (bytes)
    char* ws = (char*)d_ws;
    short* wdyn = (short*)ws;                                    // M*16384*2
    short* WgF  = (short*)(ws + (size_t)M * NOUT * 2);           // 16384*256*2
    short* qcF  = (short*)(ws + (size_t)M * NOUT * 2 + (size_t)NOUT * HIDDEN * 2);

    const int n4 = (M * HIDDEN) / 4;
    const int prepBlocks = 1024 + (n4 + 255) / 256;
    kPrep<<<prepBlocks, 256, 0, stream>>>(Wg, WgF, qc, qcF, n4);

    const int nMB = (M + 127) / 128;      // 19
    kA6<<<nMB * 128, 256, 0, stream>>>(qcF, WgF, bg, wdyn, M);

    kB8<<<(M + 1) / 2, 256, 0, stream>>>(x, wdyn, gamma, beta, out, M);
}